// Round 2
// baseline (324.682 us; speedup 1.0000x reference)
//
#include <hip/hip_runtime.h>

// Problem constants (match reference)
#define NUM_P      16
#define STEP       4
#define NUM_BLOCKS 256   // blocks per permutation (DIM / STEP)
#define DIM        1024
#define BATCH      4096

// Kernel A: extract block permutation from dense T, fully coalesced, and
// apply the `indices` reorder so kernel B needs no indirection.
// T[p][4r][col] has exactly one nonzero in the row, at col = 4*perm_p[r]
// (row 4r is the u=0 row of the 4x4 identity block, so col % 4 == 0).
// One thread per (p, r, col): 16 * 256 * 1024 = 4M threads reading 16 MiB
// of T contiguously (rows 4r only).
// g[i][r] = perm_{indices[i]}[r]
__global__ __launch_bounds__(256) void extract_perm_kernel(
    const float* __restrict__ T, const int* __restrict__ indices,
    int* __restrict__ g) {
    int idx = blockIdx.x * blockDim.x + threadIdx.x;  // p*(256*1024) + r*1024 + col
    int col = idx & (DIM - 1);
    int r = (idx >> 10) & (NUM_BLOCKS - 1);
    int p = idx >> 18;
    size_t off = (size_t)p * DIM * DIM + (size_t)(STEP * r) * DIM + col;
    if (T[off] != 0.0f) {
        int c = col >> 2;
        // find i with indices[i] == p (16 ints, L2-hot)
        int i = 0;
        #pragma unroll
        for (int k = 0; k < NUM_P; ++k)
            if (indices[k] == p) i = k;
        g[i * NUM_BLOCKS + r] = c;
    }
}

// Kernel B: one block per batch row b. Stage x[b] (4 KiB) in LDS once,
// then emit all 16 permuted copies with fully-coalesced float4 stores.
// LDS gather pays ~8-way bank-group conflicts — far under the HBM write floor.
__global__ __launch_bounds__(256) void gather_kernel(
    const float4* __restrict__ x4,
    const int* __restrict__ g,
    float4* __restrict__ out4) {
    __shared__ float4 row[NUM_BLOCKS];
    const int b = blockIdx.x;
    const int t = threadIdx.x;

    // Prefetch all 16 gather indices (coalesced, L2-hot) while the row loads.
    int c[NUM_P];
    #pragma unroll
    for (int i = 0; i < NUM_P; ++i)
        c[i] = g[i * NUM_BLOCKS + t];

    row[t] = x4[(size_t)b * NUM_BLOCKS + t];
    __syncthreads();

    #pragma unroll
    for (int i = 0; i < NUM_P; ++i) {
        out4[((size_t)(i * BATCH + b)) * NUM_BLOCKS + t] = row[c[i]];
    }
}

extern "C" void kernel_launch(void* const* d_in, const int* in_sizes, int n_in,
                              void* d_out, int out_size, void* d_ws, size_t ws_size,
                              hipStream_t stream) {
    const float* x       = (const float*)d_in[0];   // [BATCH, DIM] fp32
    const float* T       = (const float*)d_in[1];   // [NUM_P, DIM, DIM] fp32
    const int*   indices = (const int*)d_in[2];     // [NUM_P] int32
    float* out = (float*)d_out;                     // [NUM_P*BATCH, DIM] fp32

    int* g = (int*)d_ws;                            // NUM_P * NUM_BLOCKS ints (16 KiB)

    // Kernel A: 16*256*1024 = 4,194,304 threads, coalesced T read
    {
        int total = NUM_P * NUM_BLOCKS * DIM;
        extract_perm_kernel<<<dim3(total / 256), dim3(256), 0, stream>>>(T, indices, g);
    }

    // Kernel B: one block per batch row
    {
        gather_kernel<<<dim3(BATCH), dim3(256), 0, stream>>>(
            (const float4*)x, g, (float4*)out);
    }
    (void)in_sizes; (void)n_in; (void)out_size; (void)ws_size;
}